// Round 20
// baseline (674.917 us; speedup 1.0000x reference)
//
#include <hip/hip_runtime.h>
#include <hip/hip_bf16.h>

#define B_ 4
#define C_ 512
#define L_ 2048
#define H_ 8
#define E_ 64
// sqrt(0.125 * log2(e)) — folded into Q (and K=Q) so QK^T yields log2-domain scores
#define QSCALE 0.4246609f
#define NUNITS_B 2048   // units per batch: 8 h x 128 qt16 x 2 chalf

typedef __attribute__((ext_vector_type(8))) short bf16x8;
typedef __attribute__((ext_vector_type(4))) float f32x4;
typedef __attribute__((ext_vector_type(4))) unsigned short u16x4;

static __device__ __forceinline__ unsigned short f2bf(float f) {
    union { float f; unsigned u; } v; v.f = f;
    unsigned r = v.u + 0x7FFFu + ((v.u >> 16) & 1u);
    return (unsigned short)(r >> 16);
}

// ---------------- Pass A: cast x -> xb (bf16, [b][c][l]) and xt (bf16, [b][l][c]) ----------------
__global__ __launch_bounds__(256) void prep_kernel(const float* __restrict__ x,
                                                   unsigned short* __restrict__ xb,
                                                   unsigned short* __restrict__ xt) {
    const int lt = blockIdx.x, ct = blockIdx.y, b = blockIdx.z;
    const int l0 = lt * 64, c0 = ct * 64;
    const int t = threadIdx.x;
    __shared__ unsigned short T[64 * 72];

    const int cl = t >> 2, lo = (t & 3) * 16;
    const float* src = x + ((size_t)(b * C_ + c0 + cl)) * L_ + l0 + lo;
    unsigned short u[16];
    #pragma unroll
    for (int j = 0; j < 16; j += 4) {
        float4 v = *reinterpret_cast<const float4*>(src + j);
        u[j] = f2bf(v.x); u[j + 1] = f2bf(v.y); u[j + 2] = f2bf(v.z); u[j + 3] = f2bf(v.w);
    }
    unsigned short* xbp = xb + ((size_t)(b * C_ + c0 + cl)) * L_ + l0 + lo;
    reinterpret_cast<uint4*>(xbp)[0] = reinterpret_cast<uint4*>(u)[0];
    reinterpret_cast<uint4*>(xbp)[1] = reinterpret_cast<uint4*>(u)[1];
    reinterpret_cast<uint4*>(&T[cl * 72 + lo])[0] = reinterpret_cast<uint4*>(u)[0];
    reinterpret_cast<uint4*>(&T[cl * 72 + lo + 8])[0] = reinterpret_cast<uint4*>(u)[1];
    __syncthreads();
    const int ll = t >> 2, co = (t & 3) * 16;
    unsigned short v16[16];
    #pragma unroll
    for (int j = 0; j < 16; ++j) v16[j] = T[(co + j) * 72 + ll];
    unsigned short* xtp = xt + ((size_t)b * L_ + l0 + ll) * C_ + c0 + co;
    reinterpret_cast<uint4*>(xtp)[0] = reinterpret_cast<uint4*>(v16)[0];
    reinterpret_cast<uint4*>(xtp)[1] = reinterpret_cast<uint4*>(v16)[1];
}

// ---------------- Pass A2: cast W fp32 -> bf16 ----------------
__global__ __launch_bounds__(256) void wcast_kernel(const float* __restrict__ W,
                                                    unsigned short* __restrict__ Wb) {
    const int i = blockIdx.x * 256 + threadIdx.x;
    float4 v = reinterpret_cast<const float4*>(W)[i];
    union { unsigned short u[4]; unsigned long long ll; } o;
    o.u[0] = f2bf(v.x); o.u[1] = f2bf(v.y); o.u[2] = f2bf(v.z); o.u[3] = f2bf(v.w);
    reinterpret_cast<unsigned long long*>(Wb)[i] = o.ll;
}

// ---------------- Pass B: Q = (W x + b) * QSCALE, bf16 [(b*H+h)][l][e] ----------------
__global__ __launch_bounds__(256) void proj_kernel(const unsigned short* __restrict__ Wb,
                                                   const float* __restrict__ bq,
                                                   const unsigned short* __restrict__ xt,
                                                   unsigned short* __restrict__ qb) {
    const int lt = blockIdx.x, h = blockIdx.y, b = blockIdx.z;
    const int tid = threadIdx.x, w = tid >> 6, lane = tid & 63;
    const int lr = lane & 15, lg = lane >> 4;
    const int l = lt * 64 + w * 16 + lr;
    const int o0 = h * 64;

    f32x4 acc[4] = {};
    const unsigned short* xrow = xt + ((size_t)b * L_ + l) * C_;
    for (int ks = 0; ks < 16; ++ks) {
        bf16x8 bf = *reinterpret_cast<const bf16x8*>(xrow + ks * 32 + lg * 8);
        #pragma unroll
        for (int mt = 0; mt < 4; ++mt) {
            bf16x8 af = *reinterpret_cast<const bf16x8*>(Wb + (size_t)(o0 + mt * 16 + lr) * C_ + ks * 32 + lg * 8);
            acc[mt] = __builtin_amdgcn_mfma_f32_16x16x32_bf16(af, bf, acc[mt], 0, 0, 0);
        }
    }
    const int bh = b * H_ + h;
    unsigned short* qrow = qb + ((size_t)bh * L_ + l) * 64;
    #pragma unroll
    for (int mt = 0; mt < 4; ++mt) {
        const int e0 = mt * 16 + lg * 4;
        const float4 bb = *reinterpret_cast<const float4*>(bq + o0 + e0);
        union { unsigned short u[4]; unsigned long long ll; } o;
        o.u[0] = f2bf((acc[mt][0] + bb.x) * QSCALE);
        o.u[1] = f2bf((acc[mt][1] + bb.y) * QSCALE);
        o.u[2] = f2bf((acc[mt][2] + bb.z) * QSCALE);
        o.u[3] = f2bf((acc[mt][3] + bb.w) * QSCALE);
        *reinterpret_cast<unsigned long long*>(qrow + e0) = o.ll;
    }
}

// ---------------- Pass C: wave-independent flash attention, zero barriers ----------------
// One wave = one unit (16 q-rows x 256 channels). P lives in a wave-private LDS tile.
// PPAD = padded P row stride in elems (16 rows x 72 = 2304 B per block)

// Load V group G (4 c-tiles x 1 k-half) into bank BK: c-tiles (G&3)*4..+3, k-half G>>2
#define LDVG(BK, G)                                                                     \
    {                                                                                   \
        _Pragma("unroll")                                                               \
        for (int c4 = 0; c4 < 4; ++c4)                                                  \
            vf[BK][c4] = *reinterpret_cast<const bf16x8*>(                              \
                Vbase + (size_t)(c0w + ((G) & 3) * 64 + c4 * 16 + lr) * L_              \
                      + k0 + ((G) >> 2) * 32 + lg * 8);                                 \
    }

// Consume bank BK for group G: 4 MFMAs into acc[(G&3)*4 + c4], A-operand pa[G>>2]
#define PVG(BK, G)                                                                      \
    {                                                                                   \
        _Pragma("unroll")                                                               \
        for (int c4 = 0; c4 < 4; ++c4)                                                  \
            acc[((G) & 3) * 4 + c4] = __builtin_amdgcn_mfma_f32_16x16x32_bf16(          \
                pa[(G) >> 2], vf[BK][c4], acc[((G) & 3) * 4 + c4], 0, 0, 0);            \
    }

// S sub-phase for subtile S2 (16 k), MASKED = causal-mask path
#define S_SUB(S2, MASKED)                                                               \
    {                                                                                   \
        f32x4 z = {};                                                                   \
        z = __builtin_amdgcn_mfma_f32_16x16x32_bf16(kb[S2][0], qf0, z, 0, 0, 0);        \
        z = __builtin_amdgcn_mfma_f32_16x16x32_bf16(kb[S2][1], qf1, z, 0, 0, 0);        \
        float p0, p1, p2, p3;                                                           \
        if (MASKED) {                                                                   \
            const int kbase = k0 + (S2) * 16 + lg * 4;                                  \
            p0 = (kbase + 0 <= q) ? __builtin_amdgcn_exp2f(z[0]) : 0.f;                 \
            p1 = (kbase + 1 <= q) ? __builtin_amdgcn_exp2f(z[1]) : 0.f;                 \
            p2 = (kbase + 2 <= q) ? __builtin_amdgcn_exp2f(z[2]) : 0.f;                 \
            p3 = (kbase + 3 <= q) ? __builtin_amdgcn_exp2f(z[3]) : 0.f;                 \
        } else {                                                                        \
            p0 = __builtin_amdgcn_exp2f(z[0]);                                          \
            p1 = __builtin_amdgcn_exp2f(z[1]);                                          \
            p2 = __builtin_amdgcn_exp2f(z[2]);                                          \
            p3 = __builtin_amdgcn_exp2f(z[3]);                                          \
        }                                                                               \
        rs += (p0 + p1) + (p2 + p3);                                                    \
        unsigned r01, r23;                                                              \
        asm("v_cvt_pk_bf16_f32 %0, %1, %2" : "=v"(r01) : "v"(p0), "v"(p1));             \
        asm("v_cvt_pk_bf16_f32 %0, %1, %2" : "=v"(r23) : "v"(p2), "v"(p3));             \
        const unsigned long long pk = ((unsigned long long)r23 << 32) | r01;            \
        *reinterpret_cast<unsigned long long*>(&P[lr * 72 + (S2) * 16 + lg * 4]) = pk;  \
    }

__global__ __launch_bounds__(64, 2) void pv_kernel(const unsigned short* __restrict__ qb,
                                                   const unsigned short* __restrict__ xb,
                                                   float* __restrict__ out,
                                                   int* __restrict__ counters) {
    const int lane = threadIdx.x;
    const int lr = lane & 15, lg = lane >> 4;
    // batch pinned by blockIdx (XCD round-robin heuristic): 512 blocks per batch
    const int myb = (blockIdx.x & 7) >> 1;

    __shared__ unsigned short P[16 * 72];        // wave-private P tile (2304 B)

    const int b = myb;
    const unsigned short* Vbase = xb + (size_t)b * C_ * L_;
    const unsigned short* xres = xb + (size_t)b * C_ * L_;

    for (;;) {
        int u0;
        if (lane == 0) u0 = atomicAdd(counters + myb, 1);
        const int u = __shfl(u0, 0);
        if (u >= NUNITS_B) return;

        // heavy q-tiles first (LPT packing on the per-batch dynamic queue)
        const int qt16 = 127 - (u >> 4);
        const int h = (u >> 1) & 7;
        const int chalf = u & 1;
        const int q0 = qt16 * 16, qlim = q0 + 15;
        const int q = q0 + lr;                   // this lane's q-row (QK phase)
        const int nkt = (qt16 >> 2) + 1;         // 64k steps
        const int c0w = chalf * 256;
        const int bh = b * H_ + h;
        const unsigned short* Qbase = qb + (size_t)bh * L_ * 64;

        // Q B-frags: col=q=lr, e = lg*8.. (+32); persistent for the whole unit
        const bf16x8 qf0 = *reinterpret_cast<const bf16x8*>(Qbase + (size_t)(q0 + lr) * 64 + lg * 8);
        const bf16x8 qf1 = *reinterpret_cast<const bf16x8*>(Qbase + (size_t)(q0 + lr) * 64 + 32 + lg * 8);

        f32x4 acc[16] = {};
        float rs = 0.f;
        bf16x8 vf[2][4];                         // dual-bank V prefetch

        #pragma unroll 1
        for (int kt = 0; kt < nkt; ++kt) {
            const int k0 = kt * 64;

            // ---- K A-frags (row=k=lr, e = lg*8..): 8 x b128 direct from global ----
            bf16x8 kb[4][2];
            #pragma unroll
            for (int s2 = 0; s2 < 4; ++s2) {
                const size_t krow = (size_t)(k0 + s2 * 16 + lr) * 64;
                kb[s2][0] = *reinterpret_cast<const bf16x8*>(Qbase + krow + lg * 8);
                kb[s2][1] = *reinterpret_cast<const bf16x8*>(Qbase + krow + 32 + lg * 8);
            }

            // ---- S phase: z -> exp -> pack -> wave-private P (no barrier!) ----
            if (k0 + 63 <= q0) {
                S_SUB(0, 0) S_SUB(1, 0) S_SUB(2, 0) S_SUB(3, 0)
            } else {
                S_SUB(0, 1) S_SUB(1, 1) S_SUB(2, 1) S_SUB(3, 1)
            }

            // ---- PV A-frags from P (same-wave LDS; compiler inserts lgkmcnt) ----
            bf16x8 pa[2];
            pa[0] = *reinterpret_cast<const bf16x8*>(&P[lr * 72 + lg * 8]);
            pa[1] = *reinterpret_cast<const bf16x8*>(&P[lr * 72 + 32 + lg * 8]);

            // ---- PV: 16 c-tiles x 2 k-halves, dual-bank distance-1 prefetch ----
            const bool full = (k0 + 32 <= qlim);   // upper k-half live?
            LDVG(0, 0)
            LDVG(1, 1) PVG(0, 0)
            LDVG(0, 2) PVG(1, 1)
            LDVG(1, 3) PVG(0, 2)
            if (full) {
                LDVG(0, 4) PVG(1, 3)
                LDVG(1, 5) PVG(0, 4)
                LDVG(0, 6) PVG(1, 5)
                LDVG(1, 7) PVG(0, 6)
                PVG(1, 7)
            } else {
                PVG(1, 3)
            }
        }

        // ---- rowsum reduce across lg groups; li per output q-row ----
        rs += __shfl_xor(rs, 16);
        rs += __shfl_xor(rs, 32);
        f32x4 li;
        #pragma unroll
        for (int r = 0; r < 4; ++r) li[r] = 1.f / __shfl(rs, lg * 4 + r);

        // ---- epilogue: bf16 residual + NT streaming stores ----
        float* ob = out + (size_t)bh * C_ * L_;
        const int lbase = q0 + lg * 4;
        #pragma unroll
        for (int ct = 0; ct < 16; ++ct) {
            const int c = c0w + ct * 16 + lr;
            const u16x4 rv = __builtin_nontemporal_load(
                reinterpret_cast<const u16x4*>(xres + (size_t)c * L_ + lbase));
            f32x4 o;
            o[0] = acc[ct][0] * li[0] + __uint_as_float((unsigned)rv[0] << 16);
            o[1] = acc[ct][1] * li[1] + __uint_as_float((unsigned)rv[1] << 16);
            o[2] = acc[ct][2] * li[2] + __uint_as_float((unsigned)rv[2] << 16);
            o[3] = acc[ct][3] * li[3] + __uint_as_float((unsigned)rv[3] << 16);
            __builtin_nontemporal_store(o, reinterpret_cast<f32x4*>(ob + (size_t)c * L_ + lbase));
        }
    }
}

extern "C" void kernel_launch(void* const* d_in, const int* in_sizes, int n_in,
                              void* d_out, int out_size, void* d_ws, size_t ws_size,
                              hipStream_t stream) {
    const float* x  = (const float*)d_in[0];
    const float* Wq = (const float*)d_in[1];
    const float* bq = (const float*)d_in[2];
    float* out = (float*)d_out;

    unsigned short* xb   = (unsigned short*)d_ws;                        // B*C*L bf16   = 8 MiB
    unsigned short* xt   = xb + (size_t)B_ * C_ * L_;                    // B*L*C bf16   = 8 MiB
    unsigned short* qbuf = xt + (size_t)B_ * L_ * C_;                    // B*H*L*E bf16 = 8 MiB
    unsigned short* Wb   = qbuf + (size_t)B_ * H_ * L_ * E_;             // 512 KiB
    int* counters = (int*)(Wb + (size_t)H_ * E_ * C_);                   // 16 B (one per batch)

    (void)hipMemsetAsync(counters, 0, 16, stream);
    prep_kernel<<<dim3(32, 8, 4), 256, 0, stream>>>(x, xb, xt);
    wcast_kernel<<<dim3(256), 256, 0, stream>>>(Wq, Wb);
    proj_kernel<<<dim3(32, 8, 4), 256, 0, stream>>>(Wb, bq, xt, qbuf);
    pv_kernel<<<dim3(2048), 64, 0, stream>>>(qbuf, xb, out, counters);
}

// Round 22
// 281.261 us; speedup vs baseline: 2.3996x; 2.3996x over previous
//
#include <hip/hip_runtime.h>
#include <hip/hip_bf16.h>

#define B_ 4
#define C_ 512
#define L_ 2048
#define H_ 8
#define E_ 64
// sqrt(0.125 * log2(e)) — folded into Q (and K=Q) so QK^T yields log2-domain scores
#define QSCALE 0.4246609f
#define NUNITS_B 512   // units per batch: 8 h x 32 qt x 2 chalf

typedef __attribute__((ext_vector_type(8))) short bf16x8;
typedef __attribute__((ext_vector_type(4))) float f32x4;
typedef __attribute__((ext_vector_type(4))) unsigned short u16x4;

static __device__ __forceinline__ unsigned short f2bf(float f) {
    union { float f; unsigned u; } v; v.f = f;
    unsigned r = v.u + 0x7FFFu + ((v.u >> 16) & 1u);
    return (unsigned short)(r >> 16);
}

// light barrier: make LDS writes visible, do NOT drain vmcnt (loads stay in flight)
#define LBAR() do { asm volatile("s_waitcnt lgkmcnt(0)" ::: "memory"); \
                    __builtin_amdgcn_s_barrier(); } while (0)

// ---------------- Pass A: cast x -> xb (bf16, [b][c][l]) and xt (bf16, [b][l][c]) ----------------
__global__ __launch_bounds__(256) void prep_kernel(const float* __restrict__ x,
                                                   unsigned short* __restrict__ xb,
                                                   unsigned short* __restrict__ xt) {
    const int lt = blockIdx.x, ct = blockIdx.y, b = blockIdx.z;
    const int l0 = lt * 64, c0 = ct * 64;
    const int t = threadIdx.x;
    __shared__ unsigned short T[64 * 72];

    const int cl = t >> 2, lo = (t & 3) * 16;
    const float* src = x + ((size_t)(b * C_ + c0 + cl)) * L_ + l0 + lo;
    unsigned short u[16];
    #pragma unroll
    for (int j = 0; j < 16; j += 4) {
        float4 v = *reinterpret_cast<const float4*>(src + j);
        u[j] = f2bf(v.x); u[j + 1] = f2bf(v.y); u[j + 2] = f2bf(v.z); u[j + 3] = f2bf(v.w);
    }
    unsigned short* xbp = xb + ((size_t)(b * C_ + c0 + cl)) * L_ + l0 + lo;
    reinterpret_cast<uint4*>(xbp)[0] = reinterpret_cast<uint4*>(u)[0];
    reinterpret_cast<uint4*>(xbp)[1] = reinterpret_cast<uint4*>(u)[1];
    reinterpret_cast<uint4*>(&T[cl * 72 + lo])[0] = reinterpret_cast<uint4*>(u)[0];
    reinterpret_cast<uint4*>(&T[cl * 72 + lo + 8])[0] = reinterpret_cast<uint4*>(u)[1];
    __syncthreads();
    const int ll = t >> 2, co = (t & 3) * 16;
    unsigned short v16[16];
    #pragma unroll
    for (int j = 0; j < 16; ++j) v16[j] = T[(co + j) * 72 + ll];
    unsigned short* xtp = xt + ((size_t)b * L_ + l0 + ll) * C_ + c0 + co;
    reinterpret_cast<uint4*>(xtp)[0] = reinterpret_cast<uint4*>(v16)[0];
    reinterpret_cast<uint4*>(xtp)[1] = reinterpret_cast<uint4*>(v16)[1];
}

// ---------------- Pass A2: cast W fp32 -> bf16 ----------------
__global__ __launch_bounds__(256) void wcast_kernel(const float* __restrict__ W,
                                                    unsigned short* __restrict__ Wb) {
    const int i = blockIdx.x * 256 + threadIdx.x;
    float4 v = reinterpret_cast<const float4*>(W)[i];
    union { unsigned short u[4]; unsigned long long ll; } o;
    o.u[0] = f2bf(v.x); o.u[1] = f2bf(v.y); o.u[2] = f2bf(v.z); o.u[3] = f2bf(v.w);
    reinterpret_cast<unsigned long long*>(Wb)[i] = o.ll;
}

// ---------------- Pass B: Q = (W x + b) * QSCALE, bf16 [(b*H+h)][l][e] ----------------
__global__ __launch_bounds__(256) void proj_kernel(const unsigned short* __restrict__ Wb,
                                                   const float* __restrict__ bq,
                                                   const unsigned short* __restrict__ xt,
                                                   unsigned short* __restrict__ qb) {
    const int lt = blockIdx.x, h = blockIdx.y, b = blockIdx.z;
    const int tid = threadIdx.x, w = tid >> 6, lane = tid & 63;
    const int lr = lane & 15, lg = lane >> 4;
    const int l = lt * 64 + w * 16 + lr;
    const int o0 = h * 64;

    f32x4 acc[4] = {};
    const unsigned short* xrow = xt + ((size_t)b * L_ + l) * C_;
    for (int ks = 0; ks < 16; ++ks) {
        bf16x8 bf = *reinterpret_cast<const bf16x8*>(xrow + ks * 32 + lg * 8);
        #pragma unroll
        for (int mt = 0; mt < 4; ++mt) {
            bf16x8 af = *reinterpret_cast<const bf16x8*>(Wb + (size_t)(o0 + mt * 16 + lr) * C_ + ks * 32 + lg * 8);
            acc[mt] = __builtin_amdgcn_mfma_f32_16x16x32_bf16(af, bf, acc[mt], 0, 0, 0);
        }
    }
    const int bh = b * H_ + h;
    unsigned short* qrow = qb + ((size_t)bh * L_ + l) * 64;
    #pragma unroll
    for (int mt = 0; mt < 4; ++mt) {
        const int e0 = mt * 16 + lg * 4;
        const float4 bb = *reinterpret_cast<const float4*>(bq + o0 + e0);
        union { unsigned short u[4]; unsigned long long ll; } o;
        o.u[0] = f2bf((acc[mt][0] + bb.x) * QSCALE);
        o.u[1] = f2bf((acc[mt][1] + bb.y) * QSCALE);
        o.u[2] = f2bf((acc[mt][2] + bb.z) * QSCALE);
        o.u[3] = f2bf((acc[mt][3] + bb.w) * QSCALE);
        *reinterpret_cast<unsigned long long*>(qrow + e0) = o.ll;
    }
}

// ---------------- Pass C: fused attention, KBLK=512, 32c waves, 4 waves/SIMD ----------------
// V loads for 32k-step at k-offset KOFF into bank BK (2 x b128, wave's 32 channels)
#define LDVB(BK, KOFF)                                                                  \
    {                                                                                   \
        _Pragma("unroll")                                                               \
        for (int ct = 0; ct < 2; ++ct)                                                  \
            pvv[BK][ct] = *reinterpret_cast<const bf16x8*>(                             \
                Vbase + (size_t)(c0w + ct * 16 + lr) * L_ + (KOFF) + lg * 8);           \
    }

// PV step S_: consume bank CUR, prefetch step S_+1 into bank NXT (2-bank ring, dist 1); 8 MFMAs
#define PV_STEP(CUR, NXT, S_)                                                           \
    {                                                                                   \
        const int s_ = (S_);                                                            \
        if (s_ + 1 < ksmax) LDVB(NXT, k0 + (s_ + 1) * 32)                               \
        bf16x8 pa[4];                                                                   \
        _Pragma("unroll")                                                               \
        for (int mt = 0; mt < 4; ++mt) {                                                \
            const int row = mt * 16 + lr;                                               \
            const int g2 = (s_ * 4 + lg) ^ (lr & 7);                                    \
            pa[mt] = *reinterpret_cast<const bf16x8*>(&P[row * 512 + (g2 << 3)]);       \
        }                                                                               \
        __builtin_amdgcn_s_setprio(1);                                                  \
        _Pragma("unroll")                                                               \
        for (int mt = 0; mt < 4; ++mt)                                                  \
            _Pragma("unroll")                                                           \
            for (int ct = 0; ct < 2; ++ct)                                              \
                acc[mt][ct] = __builtin_amdgcn_mfma_f32_16x16x32_bf16(                  \
                    pa[mt], pvv[CUR][ct], acc[mt][ct], 0, 0, 0);                        \
        __builtin_amdgcn_s_setprio(0);                                                  \
    }

// S phase body (R19-proven, unchanged): MASKED = 0 skips all compare/select VALU
#define S_PHASE(MASKED)                                                                          \
    {                                                                                            \
        bf16x8 kb[4][2];                                                                         \
        _Pragma("unroll")                                                                        \
        for (int ksub = 0; ksub < 4; ++ksub) {                                                   \
            const size_t krow = (size_t)(kw0 + ksub * 16 + lr) * 64;                             \
            kb[ksub][0] = *reinterpret_cast<const bf16x8*>(Qbase + krow + lg * 8);               \
            kb[ksub][1] = *reinterpret_cast<const bf16x8*>(Qbase + krow + 32 + lg * 8);          \
        }                                                                                        \
        _Pragma("unroll")                                                                        \
        for (int nt = 0; nt < 4; ++nt) {                                                         \
            const int qrow = nt * 16 + lr;                                                       \
            bf16x8 aq0 = *reinterpret_cast<const bf16x8*>(&Qt[qrow * 64 + ((lg ^ (lr & 7)) << 3)]);        \
            bf16x8 aq1 = *reinterpret_cast<const bf16x8*>(&Qt[qrow * 64 + (((4 + lg) ^ (lr & 7)) << 3)]);  \
            const int q = q0 + qrow;                                                             \
            _Pragma("unroll")                                                                    \
            for (int ksub = 0; ksub < 4; ++ksub) {                                               \
                f32x4 z = {};                                                                    \
                z = __builtin_amdgcn_mfma_f32_16x16x32_bf16(kb[ksub][0], aq0, z, 0, 0, 0);       \
                z = __builtin_amdgcn_mfma_f32_16x16x32_bf16(kb[ksub][1], aq1, z, 0, 0, 0);       \
                float p0, p1, p2, p3;                                                            \
                if (MASKED) {                                                                    \
                    const int kbase = kw0 + ksub * 16 + lg * 4;                                  \
                    p0 = (kbase + 0 <= q) ? __builtin_amdgcn_exp2f(z[0]) : 0.f;                  \
                    p1 = (kbase + 1 <= q) ? __builtin_amdgcn_exp2f(z[1]) : 0.f;                  \
                    p2 = (kbase + 2 <= q) ? __builtin_amdgcn_exp2f(z[2]) : 0.f;                  \
                    p3 = (kbase + 3 <= q) ? __builtin_amdgcn_exp2f(z[3]) : 0.f;                  \
                } else {                                                                         \
                    p0 = __builtin_amdgcn_exp2f(z[0]);                                           \
                    p1 = __builtin_amdgcn_exp2f(z[1]);                                           \
                    p2 = __builtin_amdgcn_exp2f(z[2]);                                           \
                    p3 = __builtin_amdgcn_exp2f(z[3]);                                           \
                }                                                                                \
                rs[nt] += (p0 + p1) + (p2 + p3);                                                 \
                unsigned r01, r23;                                                               \
                asm("v_cvt_pk_bf16_f32 %0, %1, %2" : "=v"(r01) : "v"(p0), "v"(p1));              \
                asm("v_cvt_pk_bf16_f32 %0, %1, %2" : "=v"(r23) : "v"(p2), "v"(p3));              \
                const int kl = w * 64 + ksub * 16 + lg * 4;                                      \
                const int gg = (kl >> 3) ^ (qrow & 7);                                           \
                const unsigned long long pk = ((unsigned long long)r23 << 32) | r01;             \
                *reinterpret_cast<unsigned long long*>(&P[qrow * 512 + (gg << 3) + (kl & 7)]) = pk; \
            }                                                                                    \
        }                                                                                        \
    }

__global__ __launch_bounds__(512, 4) void pv_kernel(const unsigned short* __restrict__ qb,
                                                    const unsigned short* __restrict__ xb,
                                                    float* __restrict__ out,
                                                    int* __restrict__ counters) {
    const int tid = threadIdx.x, w = tid >> 6, lane = tid & 63;
    const int lr = lane & 15, lg = lane >> 4;
    // batch pinned by blockIdx (XCD round-robin heuristic): 128 blocks per batch
    const int myb = (blockIdx.x & 7) >> 1;

    __shared__ unsigned short Qt[64 * 64];       // swizzled Q tile (8 KB)
    __shared__ unsigned short P[64 * 512];       // 64q x 512k bf16, XOR-swizzled (64 KB)
    __shared__ float rsT[64][8];                 // per-S-wave rowsum partials (2 KB)
    __shared__ int s_u;

    const int b = myb;
    const unsigned short* Vbase = xb + (size_t)b * C_ * L_;

    for (;;) {
        // WAR on s_u only — plain barrier, NO vmcnt drain (NT stores stay in flight)
        __builtin_amdgcn_s_barrier();
        if (tid == 0) s_u = atomicAdd(counters + myb, 1);
        LBAR();   // s_u visible
        const int u = s_u;
        if (u >= NUNITS_B) return;

        // heavy q-tiles first (LPT packing on the per-batch dynamic queue)
        const int qt = 31 - (u >> 4);
        const int h = (u >> 1) & 7;
        const int chalf = u & 1;
        const int q0 = qt * 64, qlim = q0 + 63;
        const int nkt = (q0 >> 9) + 1;           // KBLK = 512
        const int bh = b * H_ + h;
        const int c0w = chalf * 256 + w * 32;    // PV: this wave's 32-channel slice
        const unsigned short* Qbase = qb + (size_t)bh * L_ * 64;

        // stage Q tile (64 rows x 64 e) into LDS, granule g -> g ^ (row&7)
        {
            const int r = tid >> 3, g = tid & 7;
            bf16x8 v = *reinterpret_cast<const bf16x8*>(Qbase + (size_t)(q0 + r) * 64 + g * 8);
            *reinterpret_cast<bf16x8*>(&Qt[r * 64 + ((g ^ (r & 7)) << 3)]) = v;
        }

        bf16x8 pvv[2][2];                        // 2-bank V ring, distance-1 (16 VGPRs)
        f32x4 acc[4][2] = {};                    // 32 AGPRs
        float rs[4] = {0.f, 0.f, 0.f, 0.f};

        LBAR();   // Qt visible

        #pragma unroll 1
        for (int kt = 0; kt < nkt; ++kt) {
            const int k0 = kt * 512;
            const int ksmax = min(16, ((qlim - k0) >> 5) + 1);   // even, 2..16
            const int kw0 = k0 + w * 64;                          // S: wave's 64k slice

            // ---- S phase: wave computes 64q x 64k slice of S, exp, pack to P ----
            if (kw0 + 63 <= q0) {
                S_PHASE(0)            // fully below diagonal: no mask VALU
            } else if (kw0 <= qlim) {
                S_PHASE(1)            // diagonal slice: masked
            }
            LDVB(0, k0)   // PV step-0 V loads: in flight across the barrier
            LBAR();       // P visible

            // ---- PV phase: up to 16 steps, 2-bank ring, distance-1 ----
            #pragma unroll 1
            for (int s = 0; s + 2 <= ksmax; s += 2) {
                PV_STEP(0, 1, s)
                PV_STEP(1, 0, s + 1)
            }
            LBAR();   // P consumed; next kt's S may overwrite
        }

        // rowsum: reduce over lg, publish per-wave partials, merge
        #pragma unroll
        for (int nt = 0; nt < 4; ++nt) {
            float t0 = __shfl_xor(rs[nt], 16); rs[nt] += t0;
            float t1 = __shfl_xor(rs[nt], 32); rs[nt] += t1;
        }
        if (lg == 0) {
            #pragma unroll
            for (int nt = 0; nt < 4; ++nt) rsT[nt * 16 + lr][w] = rs[nt];
        }
        LBAR();

        // epilogue: li per q, bf16 residual, NT streaming stores
        const unsigned short* xres = xb + (size_t)b * C_ * L_;
        float* ob = out + (size_t)bh * C_ * L_;
        #pragma unroll
        for (int mt = 0; mt < 4; ++mt) {
            f32x4 li;
            #pragma unroll
            for (int r = 0; r < 4; ++r) {
                const f32x4 s0 = *reinterpret_cast<const f32x4*>(&rsT[mt * 16 + lg * 4 + r][0]);
                const f32x4 s1 = *reinterpret_cast<const f32x4*>(&rsT[mt * 16 + lg * 4 + r][4]);
                li[r] = 1.f / (((s0[0] + s0[1]) + (s0[2] + s0[3])) + ((s1[0] + s1[1]) + (s1[2] + s1[3])));
            }
            const int lbase = q0 + mt * 16 + lg * 4;
            #pragma unroll
            for (int ct = 0; ct < 2; ++ct) {
                const int c = c0w + ct * 16 + lr;
                const u16x4 rv = __builtin_nontemporal_load(
                    reinterpret_cast<const u16x4*>(xres + (size_t)c * L_ + lbase));
                f32x4 o;
                o[0] = acc[mt][ct][0] * li[0] + __uint_as_float((unsigned)rv[0] << 16);
                o[1] = acc[mt][ct][1] * li[1] + __uint_as_float((unsigned)rv[1] << 16);
                o[2] = acc[mt][ct][2] * li[2] + __uint_as_float((unsigned)rv[2] << 16);
                o[3] = acc[mt][ct][3] * li[3] + __uint_as_float((unsigned)rv[3] << 16);
                __builtin_nontemporal_store(o, reinterpret_cast<f32x4*>(ob + (size_t)c * L_ + lbase));
            }
        }
    }
}

extern "C" void kernel_launch(void* const* d_in, const int* in_sizes, int n_in,
                              void* d_out, int out_size, void* d_ws, size_t ws_size,
                              hipStream_t stream) {
    const float* x  = (const float*)d_in[0];
    const float* Wq = (const float*)d_in[1];
    const float* bq = (const float*)d_in[2];
    float* out = (float*)d_out;

    unsigned short* xb   = (unsigned short*)d_ws;                        // B*C*L bf16   = 8 MiB
    unsigned short* xt   = xb + (size_t)B_ * C_ * L_;                    // B*L*C bf16   = 8 MiB
    unsigned short* qbuf = xt + (size_t)B_ * L_ * C_;                    // B*H*L*E bf16 = 8 MiB
    unsigned short* Wb   = qbuf + (size_t)B_ * H_ * L_ * E_;             // 512 KiB
    int* counters = (int*)(Wb + (size_t)H_ * E_ * C_);                   // 16 B (one per batch)

    (void)hipMemsetAsync(counters, 0, 16, stream);
    prep_kernel<<<dim3(32, 8, 4), 256, 0, stream>>>(x, xb, xt);
    wcast_kernel<<<dim3(256), 256, 0, stream>>>(Wq, Wb);
    proj_kernel<<<dim3(32, 8, 4), 256, 0, stream>>>(Wb, bq, xt, qbuf);
    pv_kernel<<<dim3(512), 512, 0, stream>>>(qbuf, xb, out, counters);
}